// Round 11
// baseline (248.671 us; speedup 1.0000x reference)
//
#include <hip/hip_runtime.h>
#include <hip/hip_bf16.h>

// ---- types ----
typedef __attribute__((ext_vector_type(8))) short short8_t;   // 8 x bf16 (4 VGPR)
typedef __attribute__((ext_vector_type(4))) float f32x4;      // MFMA acc / native float4

__device__ __forceinline__ short f2bf(float f) {
    union { float f; unsigned u; } v; v.f = f;
    unsigned r = (v.u + 0x7FFFu + ((v.u >> 16) & 1u)) >> 16;  // RNE
    return (short)r;
}
__device__ __forceinline__ float bf2f(short h) {
    union { float f; unsigned u; } c; c.u = ((unsigned)(unsigned short)h) << 16;
    return c.f;
}

// non-temporal float4 helpers (native clang vector type). nt streams bypass
// the Infinity Cache so the cached stream (G / v-resident data) survives.
__device__ __forceinline__ f32x4 ntload4(const float* p) {
    return __builtin_nontemporal_load(reinterpret_cast<const f32x4*>(p));
}
__device__ __forceinline__ void ntstore4(float* p, f32x4 v) {
    __builtin_nontemporal_store(v, reinterpret_cast<f32x4*>(p));
}

// Geometry: x[8][256][256][256] fp32. u = c in [0,128), v = c in [128,256).
// M = 262144 rows of 256. 16384 16-row tiles; 2048 tiles per batch.
// Affine trick: LN(v)@W^T = rstd*(v@W^T) - rstd*mean*rowsum(W), so the GEMM
// runs on RAW v (single pass) and normalization is a post-GEMM per-batch
// scalar affine. G = bf16(v)@bf16(W)^T is materialized bf16 in d_ws (134 MB,
// L3-resident) and consumed by a barrier-free streaming kernel B.
#define N_PER_BATCH 8388608.0f
#define LDR 264                  // padded LDS row (bf16): A-reads 2-way banks (free)
#define TILE(s) (16383 - (b + ((s) << 8)))
#define VADDR(T) (x + ((size_t)((T) >> 11) << 24) + (1u << 23) + ((size_t)((T) & 2047) << 12))
#define UADDR(T) (x + ((size_t)((T) >> 11) << 24) + ((size_t)((T) & 2047) << 12))

// ================= kernel A: GEMM on raw v + stats in one pass =============
// 1024 thr = 16 waves. Per 16-row tile: reg-staged raw bf16 v -> dbuf LDS;
// 8 MFMAs/wave (B-frags = W cols in regs); quad-transpose; G bf16 store
// (cached -> L3). Per-batch Sum/SumSq accumulated from the SAME staged fp32
// data: per-thread regs over each 8-tile batch group, wave shuffle-reduce at
// group end -> LDS, wave 0 publishes partials[batch][block]. Deterministic.
// v loads NON-TEMPORAL (no reuse); lgkmcnt-only barrier.
__global__ __launch_bounds__(1024, 4) void gemm_stats(const float* __restrict__ x,
                                                      const float* __restrict__ W,
                                                      short* __restrict__ G,
                                                      float2* __restrict__ partials) {
    __shared__ short vt[2][16 * LDR];   // 16896 B
    __shared__ float2 red2w[16];
    const int tid  = threadIdx.x;
    const int wid  = tid >> 6;
    const int lane = tid & 63;
    const int l15  = lane & 15;
    const int l4   = lane >> 4;
    const int q    = l15 & 3;
    const int qg   = l15 >> 2;

    // ---- B fragments: W[col][k], col = wid*16 + l15, k = kb*32 + l4*8 + j ----
    short8_t bfrag[8];
    {
        const float* wbase = W + (size_t)(wid * 16 + l15) * 256 + (l4 << 3);
        #pragma unroll
        for (int kb = 0; kb < 8; ++kb) {
            float4 p0 = *reinterpret_cast<const float4*>(wbase + kb * 32);
            float4 p1 = *reinterpret_cast<const float4*>(wbase + kb * 32 + 4);
            short8_t s;
            s[0] = f2bf(p0.x); s[1] = f2bf(p0.y); s[2] = f2bf(p0.z); s[3] = f2bf(p0.w);
            s[4] = f2bf(p1.x); s[5] = f2bf(p1.y); s[6] = f2bf(p1.z); s[7] = f2bf(p1.w);
            bfrag[kb] = s;
        }
    }

    const int   srow = tid >> 6;
    const int   scol = (tid & 63) << 2;
    const size_t goff = (size_t)srow * 256 + scol;
    const int   ldsw = srow * LDR + scol;
    const int   aoff = l15 * LDR + (l4 << 3);
    const int b = blockIdx.x;

    // ---- prologue: stage tile(0) raw; start v(1); init stats with tile(0) ----
    f32x4 v0 = ntload4(VADDR(TILE(0)) + goff);
    f32x4 vA = ntload4(VADDR(TILE(1)) + goff);
    {
        short4 si;
        si.x = f2bf(v0[0]); si.y = f2bf(v0[1]); si.z = f2bf(v0[2]); si.w = f2bf(v0[3]);
        *reinterpret_cast<short4*>(&vt[0][ldsw]) = si;
    }
    float accS = v0[0] + v0[1] + v0[2] + v0[3];
    float accQ = v0[0]*v0[0] + v0[1]*v0[1] + v0[2]*v0[2] + v0[3]*v0[3];
    __syncthreads();

    for (int s = 0; s < 64; ++s) {
        const int cur = s & 1;
        const int sp1 = (s + 1 < 64) ? s + 1 : 63;
        const int sp2 = (s + 2 < 64) ? s + 2 : 63;
        const int Ts  = TILE(s);
        const int Ts2 = TILE(sp2);

        // deep v prefetch (nt, stays in flight across the barrier)
        f32x4 vB = ntload4(VADDR(Ts2) + goff);

        // publish previous batch-group's block sum (red2w written at s-1)
        if ((s & 7) == 7 && wid == 0 && lane < 16) {
            float2 pr = red2w[lane];
            float r1 = pr.x, r2 = pr.y;
            r1 += __shfl_xor(r1, 8);  r2 += __shfl_xor(r2, 8);
            r1 += __shfl_xor(r1, 4);  r2 += __shfl_xor(r2, 4);
            r1 += __shfl_xor(r1, 2);  r2 += __shfl_xor(r2, 2);
            r1 += __shfl_xor(r1, 1);  r2 += __shfl_xor(r2, 1);
            if (lane == 0) partials[(7 - (s >> 3)) * 256 + b] = make_float2(r1, r2);
        }

        // ---- MFMA over K=256 (raw v) ----
        f32x4 acc = {0.f, 0.f, 0.f, 0.f};
        #pragma unroll
        for (int kb = 0; kb < 8; ++kb) {
            short8_t a = *reinterpret_cast<const short8_t*>(&vt[cur][aoff + kb * 32]);
            acc = __builtin_amdgcn_mfma_f32_16x16x32_bf16(a, bfrag[kb], acc, 0, 0, 0);
        }

        // ---- 4x4 transpose within lane quads ----
        float a0 = acc[0], a1 = acc[1], a2 = acc[2], a3 = acc[3];
        float e0 = __shfl_xor(a1, 1), e1 = __shfl_xor(a0, 1);
        float e2 = __shfl_xor(a3, 1), e3 = __shfl_xor(a2, 1);
        const bool qb0 = (q & 1);
        float w0 = qb0 ? e0 : a0;
        float w1 = qb0 ? a1 : e1;
        float w2 = qb0 ? e2 : a2;
        float w3 = qb0 ? a3 : e3;
        float t0 = __shfl_xor(w2, 2), t1 = __shfl_xor(w3, 2);
        float t2 = __shfl_xor(w0, 2), t3 = __shfl_xor(w1, 2);
        const bool qb1 = (q & 2);
        float x0 = qb1 ? t0 : w0;
        float x1 = qb1 ? t1 : w1;
        float x2 = qb1 ? w2 : t2;
        float x3 = qb1 ? w3 : t3;

        // ---- G store (bf16, cached -> L3); layout = (tile, tid) ----
        short4 g4;
        g4.x = f2bf(x0); g4.y = f2bf(x1); g4.z = f2bf(x2); g4.w = f2bf(x3);
        *reinterpret_cast<short4*>(G + ((size_t)Ts << 12) + (tid << 2)) = g4;

        // ---- stage tile(s+1) raw + accumulate its fp32 stats ----
        short4 sn;
        sn.x = f2bf(vA[0]); sn.y = f2bf(vA[1]); sn.z = f2bf(vA[2]); sn.w = f2bf(vA[3]);
        *reinterpret_cast<short4*>(&vt[cur ^ 1][ldsw]) = sn;
        if (s < 63) {   // s==63 re-stages tile 63: don't double-count
            accS += vA[0] + vA[1] + vA[2] + vA[3];
            accQ += vA[0]*vA[0] + vA[1]*vA[1] + vA[2]*vA[2] + vA[3]*vA[3];
        }
        if ((s & 7) == 6) {   // batch-group complete: wave-reduce into LDS
            float r1 = accS, r2 = accQ;
            r1 += __shfl_xor(r1, 32); r2 += __shfl_xor(r2, 32);
            r1 += __shfl_xor(r1, 16); r2 += __shfl_xor(r2, 16);
            r1 += __shfl_xor(r1, 8);  r2 += __shfl_xor(r2, 8);
            r1 += __shfl_xor(r1, 4);  r2 += __shfl_xor(r2, 4);
            r1 += __shfl_xor(r1, 2);  r2 += __shfl_xor(r2, 2);
            r1 += __shfl_xor(r1, 1);  r2 += __shfl_xor(r2, 1);
            if (lane == 0) red2w[wid] = make_float2(r1, r2);
            accS = 0.f; accQ = 0.f;
        }

        asm volatile("s_waitcnt lgkmcnt(0)" ::: "memory");
        __builtin_amdgcn_s_barrier();
        vA = vB;
    }
}

// ================= kernel B: finalize + affine + gate (pure streaming) =====
// Prologue: in-block finalize of partials -> bst[8]; rowsum(W) cooperatively;
// cK[batch][col] = bias+1 - rstd*mean*rowsumW. Main loop: barrier-free,
// descending walk (freshest G first): out = u * (rstd*G + cK). G cached
// (L3-hot), u/out non-temporal. 2-deep prefetch.
__global__ __launch_bounds__(1024) void apply_gate(const float* __restrict__ x,
                                                   const float* __restrict__ W,
                                                   const float* __restrict__ bias,
                                                   const short* __restrict__ G,
                                                   const float2* __restrict__ partials,
                                                   float* __restrict__ out) {
    __shared__ float2 red2[16];
    __shared__ float2 bst[8];
    __shared__ float rwacc[1024];
    __shared__ float cK[2048];
    const int tid  = threadIdx.x;
    const int wid  = tid >> 6;
    const int lane = tid & 63;
    const int l15  = lane & 15;
    const int l4   = lane >> 4;
    const int q    = l15 & 3;
    const int qg   = l15 >> 2;

    // rowsumW partial: col = tid>>2, quarter = tid&3 (64 elements each)
    {
        const float* wb = W + ((size_t)(tid >> 2) << 8) + ((tid & 3) << 6);
        float rs = 0.f;
        #pragma unroll
        for (int i = 0; i < 16; ++i) {
            float4 w4 = *reinterpret_cast<const float4*>(wb + (i << 2));
            rs += w4.x + w4.y + w4.z + w4.w;
        }
        rwacc[tid] = rs;
    }
    // partials reduce: wave pair (2w,2w+1) reduces batch w>>1
    {
        const int bb   = wid >> 1;
        const int half = wid & 1;
        const int li   = ((half << 6) + lane) << 1;
        float2 p0 = partials[(bb << 8) + li];
        float2 p1 = partials[(bb << 8) + li + 1];
        float s1 = p0.x + p1.x, s2 = p0.y + p1.y;
        #pragma unroll
        for (int off = 32; off; off >>= 1) {
            s1 += __shfl_down(s1, off);
            s2 += __shfl_down(s2, off);
        }
        if (lane == 0) red2[wid] = make_float2(s1, s2);
    }
    __syncthreads();
    if (tid < 8) {
        float a1 = red2[2 * tid].x + red2[2 * tid + 1].x;
        float a2 = red2[2 * tid].y + red2[2 * tid + 1].y;
        float mean = a1 / N_PER_BATCH;
        float var  = a2 / N_PER_BATCH - mean * mean;
        bst[tid] = make_float2(mean, rsqrtf(var + 1e-5f));
    }
    __syncthreads();
    #pragma unroll
    for (int i = 0; i < 2; ++i) {
        int idx = tid + (i << 10);
        int bb = idx >> 8, col = idx & 255;
        float rs = rwacc[col << 2] + rwacc[(col << 2) + 1]
                 + rwacc[(col << 2) + 2] + rwacc[(col << 2) + 3];
        cK[idx] = bias[col] + 1.f - bst[bb].y * bst[bb].x * rs;
    }
    __syncthreads();

    const int b = blockIdx.x;
    const size_t eoff = (size_t)(l4 * 4 + q) * 256 + wid * 16 + (qg << 2);
    const int col0 = wid * 16 + (qg << 2);

    short4 gA = *reinterpret_cast<const short4*>(G + ((size_t)TILE(63) << 12) + (tid << 2));
    f32x4  uA = ntload4(UADDR(TILE(63)) + eoff);
    short4 gB = *reinterpret_cast<const short4*>(G + ((size_t)TILE(62) << 12) + (tid << 2));
    f32x4  uB = ntload4(UADDR(TILE(62)) + eoff);

    for (int s = 63; s >= 0; --s) {
        const int sp = (s >= 2) ? s - 2 : 0;
        const int Ts = TILE(s), Tp = TILE(sp);
        short4 gC = *reinterpret_cast<const short4*>(G + ((size_t)Tp << 12) + (tid << 2));
        f32x4  uC = ntload4(UADDR(Tp) + eoff);

        const int bb = Ts >> 11;
        const float rstd = bst[bb].y;
        const float4 ck4 = *reinterpret_cast<const float4*>(&cK[(bb << 8) + col0]);

        f32x4 o;
        o[0] = uA[0] * (rstd * bf2f(gA.x) + ck4.x);
        o[1] = uA[1] * (rstd * bf2f(gA.y) + ck4.y);
        o[2] = uA[2] * (rstd * bf2f(gA.z) + ck4.z);
        o[3] = uA[3] * (rstd * bf2f(gA.w) + ck4.w);
        ntstore4(out + ((size_t)Ts << 12) + eoff, o);

        gA = gB; gB = gC; uA = uB; uB = uC;
    }
}

// ================= fallback (proven round-10 path) =========================
__global__ __launch_bounds__(256) void stats_partial(const float* __restrict__ x,
                                                     float2* __restrict__ partials) {
    int bid = blockIdx.x;
    int batch = bid >> 8;
    int blk   = bid & 255;
    const float* base = x + ((size_t)batch << 24) + (1u << 23) + ((size_t)blk << 15);
    int tid = threadIdx.x;
    float s1 = 0.f, s2 = 0.f;
    #pragma unroll
    for (int i = 0; i < 32; ++i) {
        float4 v = *reinterpret_cast<const float4*>(base + (size_t)(i * 256 + tid) * 4);
        s1 += v.x + v.y + v.z + v.w;
        s2 += v.x * v.x + v.y * v.y + v.z * v.z + v.w * v.w;
    }
    #pragma unroll
    for (int off = 32; off; off >>= 1) {
        s1 += __shfl_down(s1, off);
        s2 += __shfl_down(s2, off);
    }
    __shared__ float2 red[4];
    if ((tid & 63) == 0) red[tid >> 6] = make_float2(s1, s2);
    __syncthreads();
    if (tid == 0) {
        float a1 = 0.f, a2 = 0.f;
        #pragma unroll
        for (int w = 0; w < 4; ++w) { a1 += red[w].x; a2 += red[w].y; }
        // fallback layout: [batch*256 + blk] to match fused_gemm's reducer
        partials[(batch << 8) + blk] = make_float2(a1, a2);
    }
}

__global__ __launch_bounds__(1024, 4) void fused_gemm(const float* __restrict__ x,
                                                      const float* __restrict__ W,
                                                      const float* __restrict__ bias,
                                                      const float2* __restrict__ partials,
                                                      float* __restrict__ out) {
    __shared__ short vt[2][16 * LDR];
    __shared__ float2 red2[16];
    __shared__ float2 bst[8];
    const int tid  = threadIdx.x;
    const int wid  = tid >> 6;
    const int lane = tid & 63;
    const int l15  = lane & 15;
    const int l4   = lane >> 4;
    const int q    = l15 & 3;
    const int qg   = l15 >> 2;

    {
        const int bb   = wid >> 1;
        const int half = wid & 1;
        const int li   = ((half << 6) + lane) << 1;
        float2 p0 = partials[(bb << 8) + li];
        float2 p1 = partials[(bb << 8) + li + 1];
        float s1 = p0.x + p1.x, s2 = p0.y + p1.y;
        #pragma unroll
        for (int off = 32; off; off >>= 1) {
            s1 += __shfl_down(s1, off);
            s2 += __shfl_down(s2, off);
        }
        if (lane == 0) red2[wid] = make_float2(s1, s2);
        __syncthreads();
        if (tid < 8) {
            float a1 = red2[2 * tid].x + red2[2 * tid + 1].x;
            float a2 = red2[2 * tid].y + red2[2 * tid + 1].y;
            float mean = a1 / N_PER_BATCH;
            float var  = a2 / N_PER_BATCH - mean * mean;
            bst[tid] = make_float2(mean, rsqrtf(var + 1e-5f));
        }
    }

    short8_t bfrag[8];
    {
        const float* wbase = W + (size_t)(wid * 16 + l15) * 256 + (l4 << 3);
        #pragma unroll
        for (int kb = 0; kb < 8; ++kb) {
            float4 p0 = *reinterpret_cast<const float4*>(wbase + kb * 32);
            float4 p1 = *reinterpret_cast<const float4*>(wbase + kb * 32 + 4);
            short8_t s;
            s[0] = f2bf(p0.x); s[1] = f2bf(p0.y); s[2] = f2bf(p0.z); s[3] = f2bf(p0.w);
            s[4] = f2bf(p1.x); s[5] = f2bf(p1.y); s[6] = f2bf(p1.z); s[7] = f2bf(p1.w);
            bfrag[kb] = s;
        }
    }
    float4 bq = *reinterpret_cast<const float4*>(bias + wid * 16 + (qg << 2));
    bq.x += 1.f; bq.y += 1.f; bq.z += 1.f; bq.w += 1.f;

    const int   srow = tid >> 6;
    const int   scol = (tid & 63) << 2;
    const size_t goff = (size_t)srow * 256 + scol;
    const int   ldsw = srow * LDR + scol;
    const size_t eoff = (size_t)(l4 * 4 + q) * 256 + wid * 16 + (qg << 2);
    const int   aoff = l15 * LDR + (l4 << 3);
    const int b = blockIdx.x;

    __syncthreads();

    {
        const int T0 = TILE(0);
        const float2 ms0 = bst[T0 >> 11];
        float4 v0 = *reinterpret_cast<const float4*>(VADDR(T0) + goff);
        short4 si;
        si.x = f2bf((v0.x - ms0.x) * ms0.y); si.y = f2bf((v0.y - ms0.x) * ms0.y);
        si.z = f2bf((v0.z - ms0.x) * ms0.y); si.w = f2bf((v0.w - ms0.x) * ms0.y);
        *reinterpret_cast<short4*>(&vt[0][ldsw]) = si;
    }
    float4 vA = *reinterpret_cast<const float4*>(VADDR(TILE(1)) + goff);
    f32x4 uA = ntload4(UADDR(TILE(0)) + eoff);
    f32x4 uB = ntload4(UADDR(TILE(1)) + eoff);
    asm volatile("s_waitcnt lgkmcnt(0)" ::: "memory");
    __builtin_amdgcn_s_barrier();

    for (int s = 0; s < 64; ++s) {
        const int cur = s & 1;
        const int sp1 = (s + 1 < 64) ? s + 1 : 63;
        const int sp2 = (s + 2 < 64) ? s + 2 : 63;
        const int Ts  = TILE(s);
        const int Ts1 = TILE(sp1);
        const int Ts2 = TILE(sp2);

        float4 vB = *reinterpret_cast<const float4*>(VADDR(Ts2) + goff);
        f32x4 uC = ntload4(UADDR(Ts2) + eoff);
        const float2 ms1 = bst[Ts1 >> 11];

        f32x4 acc = {0.f, 0.f, 0.f, 0.f};
        #pragma unroll
        for (int kb = 0; kb < 8; ++kb) {
            short8_t a = *reinterpret_cast<const short8_t*>(&vt[cur][aoff + kb * 32]);
            acc = __builtin_amdgcn_mfma_f32_16x16x32_bf16(a, bfrag[kb], acc, 0, 0, 0);
        }

        float a0 = acc[0], a1 = acc[1], a2 = acc[2], a3 = acc[3];
        float e0 = __shfl_xor(a1, 1), e1 = __shfl_xor(a0, 1);
        float e2 = __shfl_xor(a3, 1), e3 = __shfl_xor(a2, 1);
        const bool qb0 = (q & 1);
        float w0 = qb0 ? e0 : a0;
        float w1 = qb0 ? a1 : e1;
        float w2 = qb0 ? e2 : a2;
        float w3 = qb0 ? a3 : e3;
        float t0 = __shfl_xor(w2, 2), t1v = __shfl_xor(w3, 2);
        float t2v = __shfl_xor(w0, 2), t3 = __shfl_xor(w1, 2);
        const bool qb1 = (q & 2);
        float x0 = qb1 ? t0 : w0;
        float x1 = qb1 ? t1v : w1;
        float x2 = qb1 ? w2 : t2v;
        float x3 = qb1 ? w3 : t3;

        f32x4 o;
        o[0] = uA[0] * (x0 + bq.x);
        o[1] = uA[1] * (x1 + bq.y);
        o[2] = uA[2] * (x2 + bq.z);
        o[3] = uA[3] * (x3 + bq.w);
        ntstore4(out + ((size_t)Ts << 12) + eoff, o);

        short4 sn;
        sn.x = f2bf((vA.x - ms1.x) * ms1.y); sn.y = f2bf((vA.y - ms1.x) * ms1.y);
        sn.z = f2bf((vA.z - ms1.x) * ms1.y); sn.w = f2bf((vA.w - ms1.x) * ms1.y);
        *reinterpret_cast<short4*>(&vt[cur ^ 1][ldsw]) = sn;

        asm volatile("s_waitcnt lgkmcnt(0)" ::: "memory");
        __builtin_amdgcn_s_barrier();

        vA = vB; uA = uB; uB = uC;
    }
}

extern "C" void kernel_launch(void* const* d_in, const int* in_sizes, int n_in,
                              void* d_out, int out_size, void* d_ws, size_t ws_size,
                              hipStream_t stream) {
    const float* x    = (const float*)d_in[0];
    const float* W    = (const float*)d_in[1];
    const float* bias = (const float*)d_in[2];
    float* out = (float*)d_out;

    const size_t G_BYTES = 134217728ull;          // 262144*256 bf16
    if (ws_size >= G_BYTES + 16384) {
        short*  G        = (short*)d_ws;
        float2* partials = (float2*)((char*)d_ws + G_BYTES);
        gemm_stats<<<256, 1024, 0, stream>>>(x, W, G, partials);
        apply_gate<<<256, 1024, 0, stream>>>(x, W, bias, G, partials, out);
    } else {
        float2* partials = (float2*)d_ws;
        stats_partial<<<2048, 256, 0, stream>>>(x, partials);
        fused_gemm<<<256, 1024, 0, stream>>>(x, W, bias, partials, out);
    }
}

// Round 12
// 184.681 us; speedup vs baseline: 1.3465x; 1.3465x over previous
//
#include <hip/hip_runtime.h>
#include <hip/hip_bf16.h>

// ---- types ----
typedef __attribute__((ext_vector_type(8))) short short8_t;   // 8 x bf16 (4 VGPR)
typedef __attribute__((ext_vector_type(4))) float f32x4;      // MFMA acc / native float4

__device__ __forceinline__ short f2bf(float f) {
    union { float f; unsigned u; } v; v.f = f;
    unsigned r = (v.u + 0x7FFFu + ((v.u >> 16) & 1u)) >> 16;  // RNE
    return (short)r;
}

// non-temporal float4 helpers (native clang vector type). u/out bypass the
// Infinity Cache so v (resident in L3 from stats_partial) survives for re-read.
__device__ __forceinline__ f32x4 ntload4(const float* p) {
    return __builtin_nontemporal_load(reinterpret_cast<const f32x4*>(p));
}
__device__ __forceinline__ void ntstore4(float* p, f32x4 v) {
    __builtin_nontemporal_store(v, reinterpret_cast<f32x4*>(p));
}

// Geometry: x[8][256][256][256] fp32. u = c in [0,128), v = c in [128,256).
// M = 262144 rows of 256. 16384 16-row tiles; 2048 tiles per batch.
#define N_PER_BATCH 8388608.0f
#define LDR 264                  // padded LDS row (bf16): A-reads 2-way banks (free)

// ---------------- kernel 1: per-block partial sums over v ----------------
// Cached loads on purpose: this pass populates L3 with v (freshest = end).
__global__ __launch_bounds__(256) void stats_partial(const float* __restrict__ x,
                                                     float2* __restrict__ partials) {
    int bid = blockIdx.x;
    int batch = bid >> 8;
    int blk   = bid & 255;
    const float* base = x + ((size_t)batch << 24) + (1u << 23) + ((size_t)blk << 15);
    int tid = threadIdx.x;
    float s1 = 0.f, s2 = 0.f;
    #pragma unroll
    for (int i = 0; i < 32; ++i) {
        float4 v = *reinterpret_cast<const float4*>(base + (size_t)(i * 256 + tid) * 4);
        s1 += v.x + v.y + v.z + v.w;
        s2 += v.x * v.x + v.y * v.y + v.z * v.z + v.w * v.w;
    }
    #pragma unroll
    for (int off = 32; off; off >>= 1) {
        s1 += __shfl_down(s1, off);
        s2 += __shfl_down(s2, off);
    }
    __shared__ float2 red[4];
    if ((tid & 63) == 0) red[tid >> 6] = make_float2(s1, s2);
    __syncthreads();
    if (tid == 0) {
        float a1 = 0.f, a2 = 0.f;
        #pragma unroll
        for (int w = 0; w < 4; ++w) { a1 += red[w].x; a2 += red[w].y; }
        partials[bid] = make_float2(a1, a2);
    }
}

// ---------------- kernel 2: fused finalize + normalize + GEMM + gate ------
// Prologue: each block redundantly reduces the 2048 partials (16 KB, L2) to
// per-batch (mean, rstd) in LDS. Then: REVERSE GRID-STRIDED tile walk
// (block b does tiles 16383-(b+s*256)): at s=0 the GPU touches the freshest
// v lines in L3 and walks backward; all blocks cluster in one span per
// stream. u loads / out stores non-temporal; v cached. v prefetch 2 deep,
// u 2 deep; lgkmcnt-only barrier keeps global loads in flight.
__global__ __launch_bounds__(1024, 4) void fused_gemm(const float* __restrict__ x,
                                                      const float* __restrict__ W,
                                                      const float* __restrict__ bias,
                                                      const float2* __restrict__ partials,
                                                      float* __restrict__ out) {
    __shared__ short vt[2][16 * LDR];   // 16896 B
    __shared__ float2 red2[16];
    __shared__ float2 bst[8];           // per-batch (mean, rstd)
    const int tid  = threadIdx.x;
    const int wid  = tid >> 6;
    const int lane = tid & 63;
    const int l15  = lane & 15;
    const int l4   = lane >> 4;
    const int q    = l15 & 3;
    const int qg   = l15 >> 2;

    // ---- finalize stats in-block: wave pair (2w, 2w+1) reduces batch w>>1 ----
    {
        const int bb   = wid >> 1;               // batch this wave helps reduce
        const int half = wid & 1;
        const int li   = ((half << 6) + lane) << 1;   // 0..254 step 2
        float2 p0 = partials[(bb << 8) + li];
        float2 p1 = partials[(bb << 8) + li + 1];
        float s1 = p0.x + p1.x, s2 = p0.y + p1.y;
        #pragma unroll
        for (int off = 32; off; off >>= 1) {
            s1 += __shfl_down(s1, off);
            s2 += __shfl_down(s2, off);
        }
        if (lane == 0) red2[wid] = make_float2(s1, s2);
        __syncthreads();
        if (tid < 8) {
            float a1 = red2[2 * tid].x + red2[2 * tid + 1].x;
            float a2 = red2[2 * tid].y + red2[2 * tid + 1].y;
            float mean = a1 / N_PER_BATCH;
            float var  = a2 / N_PER_BATCH - mean * mean;
            bst[tid] = make_float2(mean, rsqrtf(var + 1e-5f));
        }
    }

    // ---- B fragments: W[col][k], col = wid*16 + l15, k = kb*32 + l4*8 + j ----
    short8_t bfrag[8];
    {
        const float* wbase = W + (size_t)(wid * 16 + l15) * 256 + (l4 << 3);
        #pragma unroll
        for (int kb = 0; kb < 8; ++kb) {
            float4 p0 = *reinterpret_cast<const float4*>(wbase + kb * 32);
            float4 p1 = *reinterpret_cast<const float4*>(wbase + kb * 32 + 4);
            short8_t s;
            s[0] = f2bf(p0.x); s[1] = f2bf(p0.y); s[2] = f2bf(p0.z); s[3] = f2bf(p0.w);
            s[4] = f2bf(p1.x); s[5] = f2bf(p1.y); s[6] = f2bf(p1.z); s[7] = f2bf(p1.w);
            bfrag[kb] = s;
        }
    }
    // bias (+1) for post-transpose cols: wid*16 + qg*4 + (0..3)
    float4 bq = *reinterpret_cast<const float4*>(bias + wid * 16 + (qg << 2));
    bq.x += 1.f; bq.y += 1.f; bq.z += 1.f; bq.w += 1.f;

    // staging role: 1024 float4 per tile / 1024 thr = 1 each
    const int   srow = tid >> 6;
    const int   scol = (tid & 63) << 2;
    const size_t goff = (size_t)srow * 256 + scol;   // within-tile v offset
    const int   ldsw = srow * LDR + scol;

    // per-wave epilogue offset: row = l4*4+q, cols = wid*16 + qg*4
    const size_t eoff = (size_t)(l4 * 4 + q) * 256 + wid * 16 + (qg << 2);

    // A-frag LDS base: row = l15, k-offset = l4*8
    const int aoff = l15 * LDR + (l4 << 3);

    const int b = blockIdx.x;
    #define TILE(s) (16383 - (b + ((s) << 8)))
    #define VADDR(T) (x + ((size_t)((T) >> 11) << 24) + (1u << 23) + ((size_t)((T) & 2047) << 12))
    #define UADDR(T) (x + ((size_t)((T) >> 11) << 24) + ((size_t)((T) & 2047) << 12))

    __syncthreads();   // bst ready

    // ---- prologue: stage tile(0); start v(1); u(0), u(1) ----
    {
        const int T0 = TILE(0);
        const float2 ms0 = bst[T0 >> 11];
        float4 v0 = *reinterpret_cast<const float4*>(VADDR(T0) + goff);
        short4 s;
        s.x = f2bf((v0.x - ms0.x) * ms0.y); s.y = f2bf((v0.y - ms0.x) * ms0.y);
        s.z = f2bf((v0.z - ms0.x) * ms0.y); s.w = f2bf((v0.w - ms0.x) * ms0.y);
        *reinterpret_cast<short4*>(&vt[0][ldsw]) = s;
    }
    float4 vA = *reinterpret_cast<const float4*>(VADDR(TILE(1)) + goff);   // v(1)
    f32x4 uA = ntload4(UADDR(TILE(0)) + eoff);                             // u(0)
    f32x4 uB = ntload4(UADDR(TILE(1)) + eoff);                             // u(1)
    asm volatile("s_waitcnt lgkmcnt(0)" ::: "memory");
    __builtin_amdgcn_s_barrier();

    for (int s = 0; s < 64; ++s) {
        const int cur = s & 1;
        const int sp1 = (s + 1 < 64) ? s + 1 : 63;
        const int sp2 = (s + 2 < 64) ? s + 2 : 63;
        const int Ts  = TILE(s);
        const int Ts1 = TILE(sp1);
        const int Ts2 = TILE(sp2);

        // deep prefetches first (stay in flight across the barrier)
        float4 vB = *reinterpret_cast<const float4*>(VADDR(Ts2) + goff);
        f32x4 uC = ntload4(UADDR(Ts2) + eoff);
        const float2 ms1 = bst[Ts1 >> 11];    // stats for the tile being staged

        // ---- MFMA over K=256 ----
        f32x4 acc = {0.f, 0.f, 0.f, 0.f};
        #pragma unroll
        for (int kb = 0; kb < 8; ++kb) {
            short8_t a = *reinterpret_cast<const short8_t*>(&vt[cur][aoff + kb * 32]);
            acc = __builtin_amdgcn_mfma_f32_16x16x32_bf16(a, bfrag[kb], acc, 0, 0, 0);
        }

        // ---- 4x4 transpose within lane quads: reg r <-> lane q ----
        float a0 = acc[0], a1 = acc[1], a2 = acc[2], a3 = acc[3];
        float s0 = __shfl_xor(a1, 1), s1v = __shfl_xor(a0, 1);
        float s2v = __shfl_xor(a3, 1), s3 = __shfl_xor(a2, 1);
        const bool qb0 = (q & 1);
        float w0 = qb0 ? s0 : a0;
        float w1 = qb0 ? a1 : s1v;
        float w2 = qb0 ? s2v : a2;
        float w3 = qb0 ? a3 : s3;
        float t0 = __shfl_xor(w2, 2), t1v = __shfl_xor(w3, 2);
        float t2v = __shfl_xor(w0, 2), t3 = __shfl_xor(w1, 2);
        const bool qb1 = (q & 2);
        float x0 = qb1 ? t0 : w0;
        float x1 = qb1 ? t1v : w1;
        float x2 = qb1 ? w2 : t2v;
        float x3 = qb1 ? w3 : t3;

        // ---- epilogue: out = u * (y + b + 1), non-temporal store ----
        f32x4 o;
        o[0] = uA[0] * (x0 + bq.x);
        o[1] = uA[1] * (x1 + bq.y);
        o[2] = uA[2] * (x2 + bq.z);
        o[3] = uA[3] * (x3 + bq.w);
        ntstore4(out + ((size_t)Ts << 12) + eoff, o);

        // ---- stage tile(s+1) (vA) into other buffer, with ITS batch stats ----
        short4 sn;
        sn.x = f2bf((vA.x - ms1.x) * ms1.y); sn.y = f2bf((vA.y - ms1.x) * ms1.y);
        sn.z = f2bf((vA.z - ms1.x) * ms1.y); sn.w = f2bf((vA.w - ms1.x) * ms1.y);
        *reinterpret_cast<short4*>(&vt[cur ^ 1][ldsw]) = sn;

        // raw barrier: drain LDS only, keep global loads in flight
        asm volatile("s_waitcnt lgkmcnt(0)" ::: "memory");
        __builtin_amdgcn_s_barrier();

        vA = vB; uA = uB; uB = uC;
    }
    #undef TILE
    #undef VADDR
    #undef UADDR
}

extern "C" void kernel_launch(void* const* d_in, const int* in_sizes, int n_in,
                              void* d_out, int out_size, void* d_ws, size_t ws_size,
                              hipStream_t stream) {
    const float* x    = (const float*)d_in[0];
    const float* W    = (const float*)d_in[1];
    const float* bias = (const float*)d_in[2];
    float* out = (float*)d_out;

    float2* partials = (float2*)d_ws;                       // 2048 * 8 B

    stats_partial<<<2048, 256, 0, stream>>>(x, partials);
    fused_gemm<<<256, 1024, 0, stream>>>(x, W, bias, partials, out);
}